// Round 6
// baseline (619.133 us; speedup 1.0000x reference)
//
#include <hip/hip_runtime.h>
#include <hip/hip_bf16.h>

// MLA prefill: B=2,S=2048,DIM=2048,NH=16,D_NOPE=128,D_ROPE=64,D_V=128,KV_RANK=512
// R6: attention rebalanced — 64-q blocks (256 thr, 4 waves), grid 1024 big-first
// for greedy load balance at 3 blocks/CU (52.5 KB LDS). KS 200->208, PS 36->34
// for fewer bank conflicts. GEMMs/casts frozen from R5 (m97 glds structure).

typedef __bf16 bf16x8 __attribute__((ext_vector_type(8)));
typedef float  f32x4  __attribute__((ext_vector_type(4)));
typedef unsigned short us8 __attribute__((ext_vector_type(8)));
typedef unsigned short us4 __attribute__((ext_vector_type(4)));

#define S_LEN   2048
#define BS_TOT  4096   // B*S
#define NH      16
#define DQK     192
#define DV      128
#define KV_RANK 512

__device__ inline unsigned short f2bf(float f) {
  __hip_bfloat16 h = __float2bfloat16(f);
  return *reinterpret_cast<unsigned short*>(&h);
}
__device__ inline unsigned int pack2bf(float a, float b) {
  return (unsigned int)f2bf(a) | ((unsigned int)f2bf(b) << 16);
}
__device__ inline void glds16(const void* g, void* l) {
  __builtin_amdgcn_global_load_lds(
      (const __attribute__((address_space(1))) unsigned int*)g,
      (__attribute__((address_space(3))) unsigned int*)l, 16, 0, 0);
}

// ---------------- f32 -> bf16 cast (with zero pad to npad) ----------------
__global__ void cast_f32_bf16_kernel(const float* __restrict__ src,
                                     __hip_bfloat16* __restrict__ dst,
                                     int n, int npad) {
  int tid = blockIdx.x * blockDim.x + threadIdx.x;
  int stride = gridDim.x * blockDim.x;
  for (int i = tid * 4; i < npad; i += stride * 4) {
    if (i < n) {
      f32x4 v = *(const f32x4*)(src + i);
      dst[i + 0] = __float2bfloat16(v.x);
      dst[i + 1] = __float2bfloat16(v.y);
      dst[i + 2] = __float2bfloat16(v.z);
      dst[i + 3] = __float2bfloat16(v.w);
    } else {
      dst[i + 0] = __float2bfloat16(0.f);
      dst[i + 1] = __float2bfloat16(0.f);
      dst[i + 2] = __float2bfloat16(0.f);
      dst[i + 3] = __float2bfloat16(0.f);
    }
  }
}

// ---------------- bf16 MFMA GEMM: C[M,N] = A[M,K] @ Bw[N,K]^T ----------------
// m97 structure: global_load_lds width-16 staging, 128x128 tile, BK=32.
// Bw must have >= ceil(N/128)*128 valid rows (zero-padded if needed).
template<int OUT_BF16>
__global__ __launch_bounds__(256) void gemm_bt(const __hip_bfloat16* __restrict__ A,
                                               const __hip_bfloat16* __restrict__ Bw,
                                               void* __restrict__ Cp,
                                               int M, int N, int K) {
  constexpr int BM = 128, BN = 128, BK = 32;
  __shared__ alignas(16) unsigned short As[BM * BK];
  __shared__ alignas(16) unsigned short Bs[BN * BK];
  const int tid  = threadIdx.x;
  const int m0   = blockIdx.y * BM, n0 = blockIdx.x * BN;
  const int w    = tid >> 6, lane = tid & 63;
  const int wm   = (w >> 1) * 64, wn = (w & 1) * 64;
  const int ml   = lane & 15, quad = lane >> 4;
  const int srow = w * 16 + (lane >> 2);   // staging row within 64-row half
  const int scol = (lane & 3) * 8;         // staging col (elems)

  f32x4 acc[4][4];
#pragma unroll
  for (int i = 0; i < 4; i++)
#pragma unroll
    for (int j = 0; j < 4; j++)
#pragma unroll
      for (int e = 0; e < 4; e++) acc[i][j][e] = 0.0f;

  const unsigned short* Ag = (const unsigned short*)A;
  const unsigned short* Bg = (const unsigned short*)Bw;
  const unsigned short* a0 = Ag + (size_t)(m0 + srow) * K + scol;
  const unsigned short* a1 = Ag + (size_t)(m0 + srow + 64) * K + scol;
  const unsigned short* b0 = Bg + (size_t)(n0 + srow) * K + scol;
  const unsigned short* b1 = Bg + (size_t)(n0 + srow + 64) * K + scol;
  unsigned short* lA0 = &As[(w * 16) * BK];        // wave-uniform LDS bases
  unsigned short* lA1 = &As[(64 + w * 16) * BK];
  unsigned short* lB0 = &Bs[(w * 16) * BK];
  unsigned short* lB1 = &Bs[(64 + w * 16) * BK];

  for (int k0 = 0; k0 < K; k0 += BK) {
    __syncthreads();
    glds16(a0 + k0, lA0);
    glds16(a1 + k0, lA1);
    glds16(b0 + k0, lB0);
    glds16(b1 + k0, lB1);
    __syncthreads();

    bf16x8 af[4], bfr[4];
#pragma unroll
    for (int mi = 0; mi < 4; mi++)
      af[mi] = *(const bf16x8*)&As[(wm + mi * 16 + ml) * BK + quad * 8];
#pragma unroll
    for (int ni = 0; ni < 4; ni++)
      bfr[ni] = *(const bf16x8*)&Bs[(wn + ni * 16 + ml) * BK + quad * 8];
#pragma unroll
    for (int mi = 0; mi < 4; mi++)
#pragma unroll
      for (int ni = 0; ni < 4; ni++)
        acc[mi][ni] = __builtin_amdgcn_mfma_f32_16x16x32_bf16(af[mi], bfr[ni],
                                                              acc[mi][ni], 0, 0, 0);
  }

#pragma unroll
  for (int mi = 0; mi < 4; mi++) {
#pragma unroll
    for (int ni = 0; ni < 4; ni++) {
      int col = n0 + wn + ni * 16 + ml;
      if (col < N) {
#pragma unroll
        for (int j = 0; j < 4; j++) {
          int row = m0 + wm + mi * 16 + quad * 4 + j;
          float v = acc[mi][ni][j];
          if (OUT_BF16)
            ((__hip_bfloat16*)Cp)[(size_t)row * N + col] = __float2bfloat16(v);
          else
            ((float*)Cp)[(size_t)row * N + col] = v;
        }
      }
    }
  }
}

// ---------------- RoPE on q_pe (in place, bf16 q [BS][NH*192]) ----------------
__global__ __launch_bounds__(256) void rope_q_kernel(__hip_bfloat16* __restrict__ q,
                                                     const float* __restrict__ freqs) {
  int si = blockIdx.x;
  int s  = si & (S_LEN - 1);
  int tid = threadIdx.x;
  for (int p = tid; p < NH * 32; p += 256) {
    int h = p >> 5, i = p & 31;
    size_t base = (size_t)si * (NH * DQK) + h * DQK + 128 + 2 * i;
    float c  = freqs[s * 64 + 2 * i];
    float sn = freqs[s * 64 + 2 * i + 1];
    float x0 = __bfloat162float(q[base]);
    float x1 = __bfloat162float(q[base + 1]);
    q[base]     = __float2bfloat16(x0 * c - x1 * sn);
    q[base + 1] = __float2bfloat16(x0 * sn + x1 * c);
  }
}

// -------- RMSNorm(kv latent) -> bf16, RoPE(k_pe) -> bf16 ---------------------
__global__ __launch_bounds__(256) void rms_rope_kv_kernel(
    const float* __restrict__ kva, const float* __restrict__ w,
    const float* __restrict__ freqs, __hip_bfloat16* __restrict__ latent,
    __hip_bfloat16* __restrict__ kpe_out) {
  int si = blockIdx.x;
  int tid = threadIdx.x;
  const float* row = kva + (size_t)si * 576;
  float v0 = row[tid], v1 = row[tid + 256];
  float ss = v0 * v0 + v1 * v1;
#pragma unroll
  for (int off = 1; off < 64; off <<= 1) ss += __shfl_xor(ss, off, 64);
  __shared__ float red[4];
  if ((tid & 63) == 0) red[tid >> 6] = ss;
  __syncthreads();
  float tot = red[0] + red[1] + red[2] + red[3];
  float r = rsqrtf(tot / 512.0f + 1e-6f);
  latent[(size_t)si * 512 + tid]       = __float2bfloat16(v0 * r * w[tid]);
  latent[(size_t)si * 512 + tid + 256] = __float2bfloat16(v1 * r * w[tid + 256]);
  if (tid < 32) {
    int s = si & (S_LEN - 1);
    float c  = freqs[s * 64 + 2 * tid];
    float sn = freqs[s * 64 + 2 * tid + 1];
    float x0 = row[512 + 2 * tid], x1 = row[512 + 2 * tid + 1];
    kpe_out[(size_t)si * 64 + 2 * tid]     = __float2bfloat16(x0 * c - x1 * sn);
    kpe_out[(size_t)si * 64 + 2 * tid + 1] = __float2bfloat16(x0 * sn + x1 * c);
  }
}

// ---------------- MFMA flash attention, balanced 64-q blocks -------------------
// grid (S/64, NH, B), qt = 31-bx (big-first greedy). 256 thr = 4 waves x 16 q.
// K-tile 64; every wave computes every ktile 0..qt (diag masked in softmax).
// 3 blocks/CU (52.5 KB LDS). Register-relay prefetch, O^T=V^T·P^T swap.
__global__ __launch_bounds__(256, 3) void attn_mfma_kernel(
    const __hip_bfloat16* __restrict__ qb,    // [BS][NH*192]
    const __hip_bfloat16* __restrict__ kvup,  // [BS][NH*256] (nope|v per head)
    const __hip_bfloat16* __restrict__ kpe,   // [BS][64] bf16
    __hip_bfloat16* __restrict__ attn_out) {  // [BS][NH*128]
  constexpr int KS = 208;   // Ks row stride (elems): 104 dw ≡ 8 mod 32 -> 4-way
  constexpr int VS = 36;    // Vt2 row stride (dwords), XOR-swizzled
  constexpr int PS = 34;    // Ps row stride (dwords): ≡ 2 mod 32 -> 4-way reads
  __shared__ alignas(16) unsigned short Ks[64 * KS];    // 26624 B
  __shared__ alignas(16) unsigned int   Vt2[128 * VS];  // 18432 B
  __shared__ alignas(16) unsigned int   Ps[4][16 * PS]; //  8704 B

  const int qt = (gridDim.x - 1) - blockIdx.x;  // big blocks dispatched first
  const int h = blockIdx.y, b = blockIdx.z;
  const int tid = threadIdx.x, wave = tid >> 6, lane = tid & 63;
  const int ml = lane & 15, quad = lane >> 4;
  const int qw = qt * 64 + wave * 16;
  const float qs2 = 0.07216878364870322f * 1.4426950408889634f;  // scale*log2e

  // resident Q B-frags: n=ml -> q row qw+ml; k = kc*32 + quad*8 + j
  bf16x8 Qf[6];
  {
    const unsigned short* qrow = (const unsigned short*)qb +
        (size_t)(b * S_LEN + qw + ml) * (NH * DQK) + h * DQK;
#pragma unroll
    for (int kc = 0; kc < 6; kc++)
      Qf[kc] = *(const bf16x8*)(qrow + kc * 32 + quad * 8);
  }

  const int m16 = tid & 15;           // V: d-chunk owner
  const int hp0 = tid >> 4;           // V: k-pair index (and +16)
  const int vkey = (m16 & 7) << 2;    // V write swizzle
  const unsigned short* kvbase = (const unsigned short*)kvup;
  const unsigned short* kpbase = (const unsigned short*)kpe;

  float m_i = -1e30f, l_i = 0.0f;
  f32x4 O[8];  // O^T: reg j of tile nt = v=nt*16+quad*4+j, q=ml
#pragma unroll
  for (int nt = 0; nt < 8; nt++)
#pragma unroll
    for (int j = 0; j < 4; j++) O[nt][j] = 0.0f;

  unsigned int* myP = Ps[wave];
  const int nkt = qt + 1;

  // ---- prefetch tile 0 into registers (K: 6 chunks, V: 2 hp x 2 rows) ----
  us8 Kpre[6], Vpre[4];
  {
#pragma unroll
    for (int it = 0; it < 6; it++) {
      int i = tid + it * 256;
      int r = i / 24, c = i - r * 24;
      size_t grow = (size_t)(b * S_LEN + r);
      Kpre[it] = (c < 16)
          ? *(const us8*)(kvbase + grow * (NH * 256) + h * 256 + c * 8)
          : *(const us8*)(kpbase + grow * 64 + (c - 16) * 8);
    }
#pragma unroll
    for (int it = 0; it < 2; it++) {
      int hp = hp0 + it * 16;
      const unsigned short* v0 = kvbase +
          (size_t)(b * S_LEN + 2 * hp) * (NH * 256) + h * 256 + 128 + m16 * 8;
      Vpre[2 * it]     = *(const us8*)v0;
      Vpre[2 * it + 1] = *(const us8*)(v0 + NH * 256);
    }
  }

  for (int kt = 0; kt < nkt; kt++) {
    const int kb = kt * 64;
    __syncthreads();  // all waves done reading previous tile
    // ---- write prefetched K ----
#pragma unroll
    for (int it = 0; it < 6; it++) {
      int i = tid + it * 256;
      int r = i / 24, c = i - r * 24;
      *(us8*)&Ks[r * KS + c * 8] = Kpre[it];
    }
    // ---- write prefetched V (pair-packed, swizzled) ----
#pragma unroll
    for (int it = 0; it < 2; it++) {
      int hp = hp0 + it * 16;
#pragma unroll
      for (int z = 0; z < 8; z++) {
        int d = m16 * 8 + z;
        Vt2[d * VS + (hp ^ vkey)] =
            (unsigned)(unsigned short)Vpre[2 * it][z] |
            ((unsigned)(unsigned short)Vpre[2 * it + 1][z] << 16);
      }
    }
    __syncthreads();

    // ---- prefetch next tile ----
    if (kt + 1 < nkt) {
      const int kb2 = kb + 64;
#pragma unroll
      for (int it = 0; it < 6; it++) {
        int i = tid + it * 256;
        int r = i / 24, c = i - r * 24;
        size_t grow = (size_t)(b * S_LEN + kb2 + r);
        Kpre[it] = (c < 16)
            ? *(const us8*)(kvbase + grow * (NH * 256) + h * 256 + c * 8)
            : *(const us8*)(kpbase + grow * 64 + (c - 16) * 8);
      }
#pragma unroll
      for (int it = 0; it < 2; it++) {
        int hp = hp0 + it * 16;
        const unsigned short* v0 = kvbase +
            (size_t)(b * S_LEN + kb2 + 2 * hp) * (NH * 256) + h * 256 + 128 + m16 * 8;
        Vpre[2 * it]     = *(const us8*)v0;
        Vpre[2 * it + 1] = *(const us8*)(v0 + NH * 256);
      }
    }

    // ---- S^T = K·Q^T: rows kpos (m), cols q (n=ml) ----
    f32x4 st[4];
#pragma unroll
    for (int mt = 0; mt < 4; mt++) {
      f32x4 acc = {0.f, 0.f, 0.f, 0.f};
#pragma unroll
      for (int kc = 0; kc < 6; kc++) {
        bf16x8 kf = *(const bf16x8*)&Ks[(mt * 16 + ml) * KS + kc * 32 + quad * 8];
        acc = __builtin_amdgcn_mfma_f32_16x16x32_bf16(kf, Qf[kc], acc, 0, 0, 0);
      }
      st[mt] = acc;
    }

    // ---- online softmax in exp2 domain: lane owns q = qw+ml ----
    const int qg = qw + ml;
    float mloc = -1e30f;
#pragma unroll
    for (int mt = 0; mt < 4; mt++)
#pragma unroll
      for (int j = 0; j < 4; j++) {
        int kpos = kb + mt * 16 + quad * 4 + j;
        float s = st[mt][j] * qs2;
        s = (kpos > qg) ? -1e30f : s;
        st[mt][j] = s;
        mloc = fmaxf(mloc, s);
      }
    mloc = fmaxf(mloc, __shfl_xor(mloc, 16, 64));
    mloc = fmaxf(mloc, __shfl_xor(mloc, 32, 64));
    float m_new = fmaxf(m_i, mloc);
    float alpha = exp2f(m_i - m_new);
    float psum = 0.0f;
#pragma unroll
    for (int mt = 0; mt < 4; mt++) {
      float p0 = exp2f(st[mt][0] - m_new);
      float p1 = exp2f(st[mt][1] - m_new);
      float p2 = exp2f(st[mt][2] - m_new);
      float p3 = exp2f(st[mt][3] - m_new);
      psum += (p0 + p1) + (p2 + p3);
      myP[ml * PS + mt * 8 + quad * 2 + 0] = pack2bf(p0, p1);
      myP[ml * PS + mt * 8 + quad * 2 + 1] = pack2bf(p2, p3);
    }
    psum += __shfl_xor(psum, 16, 64);
    psum += __shfl_xor(psum, 32, 64);
    l_i = l_i * alpha + psum;
    m_i = m_new;

    // rescale O^T: all regs have q=ml -> lane-local alpha
#pragma unroll
    for (int nt = 0; nt < 8; nt++)
#pragma unroll
      for (int j = 0; j < 4; j++) O[nt][j] *= alpha;

    asm volatile("s_waitcnt lgkmcnt(0)" ::: "memory");  // P writes -> P reads

    // ---- PV as O^T = V^T·P^T: A=V^T rows (v,k), B=P rows (q,k) ----
#pragma unroll
    for (int kc = 0; kc < 2; kc++) {
      bf16x8 pf = *(const bf16x8*)&myP[ml * PS + kc * 16 + quad * 4];
#pragma unroll
      for (int nt = 0; nt < 8; nt++) {
        int vrow = nt * 16 + ml;
        const unsigned int* vp =
            &Vt2[vrow * VS + ((kc * 16 + quad * 4) ^ (((vrow >> 3) & 7) << 2))];
        bf16x8 bv = *(const bf16x8*)vp;
        O[nt] = __builtin_amdgcn_mfma_f32_16x16x32_bf16(bv, pf, O[nt], 0, 0, 0);
      }
    }
  }

  // ---- epilogue: O^T[v=nt*16+quad*4+j][q=ml]; lane-local 1/l ----
  float invl = 1.0f / l_i;
  size_t orow = (size_t)(b * S_LEN + qw + ml) * (NH * DV) + h * DV;
#pragma unroll
  for (int nt = 0; nt < 8; nt++) {
    us4 pk;
#pragma unroll
    for (int j = 0; j < 4; j++) pk[j] = f2bf(O[nt][j] * invl);
    *(us4*)((unsigned short*)attn_out + orow + nt * 16 + quad * 4) = pk;
  }
}

// ---------------- launch ----------------
extern "C" void kernel_launch(void* const* d_in, const int* in_sizes, int n_in,
                              void* d_out, int out_size, void* d_ws, size_t ws_size,
                              hipStream_t stream) {
  const float* x     = (const float*)d_in[0];
  const float* freqs = (const float*)d_in[2];
  const float* wq    = (const float*)d_in[4];
  const float* wkva  = (const float*)d_in[5];
  const float* wkvb  = (const float*)d_in[6];
  const float* wo    = (const float*)d_in[7];
  const float* kvnw  = (const float*)d_in[8];
  float* out = (float*)d_out;

  char* ws = (char*)d_ws;
  size_t off = 0;
  auto alloc = [&](size_t bytes) {
    void* p = ws + off;
    off += (bytes + 255) & ~(size_t)255;
    return p;
  };
  __hip_bfloat16* x_bf    = (__hip_bfloat16*)alloc((size_t)BS_TOT * 2048 * 2);
  __hip_bfloat16* wq_bf   = (__hip_bfloat16*)alloc((size_t)3072 * 2048 * 2);
  __hip_bfloat16* wkva_bf = (__hip_bfloat16*)alloc((size_t)640 * 2048 * 2);  // padded
  __hip_bfloat16* wkvb_bf = (__hip_bfloat16*)alloc((size_t)4096 * 512 * 2);
  __hip_bfloat16* wo_bf   = (__hip_bfloat16*)alloc((size_t)2048 * 2048 * 2);
  __hip_bfloat16* q_bf    = (__hip_bfloat16*)alloc((size_t)BS_TOT * 3072 * 2);
  float*          kva     = (float*)alloc((size_t)BS_TOT * 576 * 4);
  __hip_bfloat16* latent  = (__hip_bfloat16*)alloc((size_t)BS_TOT * 512 * 2);
  __hip_bfloat16* kpe     = (__hip_bfloat16*)alloc((size_t)BS_TOT * 64 * 2);
  __hip_bfloat16* kvup    = (__hip_bfloat16*)alloc((size_t)BS_TOT * 4096 * 2);
  __hip_bfloat16* attn    = (__hip_bfloat16*)alloc((size_t)BS_TOT * 2048 * 2);

  cast_f32_bf16_kernel<<<2048, 256, 0, stream>>>(x, x_bf, BS_TOT * 2048,
                                                 BS_TOT * 2048);
  cast_f32_bf16_kernel<<<2048, 256, 0, stream>>>(wq, wq_bf, 3072 * 2048,
                                                 3072 * 2048);
  cast_f32_bf16_kernel<<<1024, 256, 0, stream>>>(wkva, wkva_bf, 576 * 2048,
                                                 640 * 2048);
  cast_f32_bf16_kernel<<<1024, 256, 0, stream>>>(wkvb, wkvb_bf, 4096 * 512,
                                                 4096 * 512);
  cast_f32_bf16_kernel<<<2048, 256, 0, stream>>>(wo, wo_bf, 2048 * 2048,
                                                 2048 * 2048);

  gemm_bt<1><<<dim3(3072 / 128, BS_TOT / 128), 256, 0, stream>>>(
      x_bf, wq_bf, q_bf, BS_TOT, 3072, 2048);
  rope_q_kernel<<<BS_TOT, 256, 0, stream>>>(q_bf, freqs);

  gemm_bt<0><<<dim3(5, BS_TOT / 128), 256, 0, stream>>>(
      x_bf, wkva_bf, kva, BS_TOT, 576, 2048);
  rms_rope_kv_kernel<<<BS_TOT, 256, 0, stream>>>(kva, kvnw, freqs, latent, kpe);

  gemm_bt<1><<<dim3(4096 / 128, BS_TOT / 128), 256, 0, stream>>>(
      latent, wkvb_bf, kvup, BS_TOT, 4096, 512);

  attn_mfma_kernel<<<dim3(S_LEN / 64, NH, 2), 256, 0, stream>>>(
      q_bf, kvup, kpe, attn);

  gemm_bt<0><<<dim3(2048 / 128, BS_TOT / 128), 256, 0, stream>>>(
      attn, wo_bf, out, BS_TOT, 2048, 2048);
}